// Round 1
// baseline (314.747 us; speedup 1.0000x reference)
//
#include <hip/hip_runtime.h>
#include <hip/hip_bf16.h>

// Guided filter, B=8 C=3 H=W=512, RADIUS=15 (31x31 box, zero-pad, /961 always).
// Stage 1: per 32x32 tile, LDS-staged separable box sums of {gray, gray^2,
//          input_c, gray*input_c} -> a,b planes in workspace.
// Stage 2: separable box sums of {a,b} + recompute gray at center -> output.

#define TILE 32
#define RAD 15
#define HAL 62          // TILE + 2*RAD
#define HSTR 63         // halo row stride (+1 pad)
#define HW 512
#define PLANE 262144    // 512*512
#define INV_K2 (1.0f / 961.0f)

__global__ __launch_bounds__(256) void gf_stage1(
    const float* __restrict__ guide, const float* __restrict__ inp,
    float* __restrict__ a_out, float* __restrict__ b_out)
{
    __shared__ float ghalo[HAL * HSTR];
    __shared__ float phalo[HAL * HSTR];
    __shared__ float hsum0[HAL * TILE];
    __shared__ float hsum1[HAL * TILE];

    const int tx0 = blockIdx.x * TILE;
    const int ty0 = blockIdx.y * TILE;
    const int b   = blockIdx.z;
    const int tid = threadIdx.x;

    const float* gbase = guide + (size_t)b * 3 * PLANE;
    const float* pbase = inp   + (size_t)b * 3 * PLANE;

    // ---- gray halo (luma on the fly), zero outside image ----
    for (int i = tid; i < HAL * HAL; i += 256) {
        int r = i / HAL, c = i - r * HAL;
        int y = ty0 + r - RAD, x = tx0 + c - RAD;
        float v = 0.0f;
        if ((unsigned)y < (unsigned)HW && (unsigned)x < (unsigned)HW) {
            int off = y * HW + x;
            v = 0.299f * gbase[off] + 0.587f * gbase[PLANE + off]
              + 0.114f * gbase[2 * PLANE + off];
        }
        ghalo[r * HSTR + c] = v;
    }
    __syncthreads();

    // ---- horizontal sums: gray, gray^2 ----
    for (int i = tid; i < HAL * TILE; i += 256) {
        int r = i >> 5, c = i & 31;
        const float* row = &ghalo[r * HSTR + c];
        float s = 0.f, s2 = 0.f;
        #pragma unroll
        for (int k = 0; k < 31; ++k) { float v = row[k]; s += v; s2 += v * v; }
        hsum0[r * TILE + c] = s;
        hsum1[r * TILE + c] = s2;
    }
    __syncthreads();

    // ---- vertical -> mean_I, var_I (4 pixels/thread, registers) ----
    float meanI[4], varI[4];
    #pragma unroll
    for (int q = 0; q < 4; ++q) {
        int o = q * 256 + tid;
        int r = o >> 5, c = o & 31;
        float s = 0.f, s2 = 0.f;
        #pragma unroll
        for (int k = 0; k < 31; ++k) {
            s  += hsum0[(r + k) * TILE + c];
            s2 += hsum1[(r + k) * TILE + c];
        }
        float mI = s * INV_K2;
        meanI[q] = mI;
        varI[q]  = s2 * INV_K2 - mI * mI;
    }

    // ---- per input channel: mean_p, corr_Ip -> a, b ----
    for (int ch = 0; ch < 3; ++ch) {
        __syncthreads();  // hsum/phalo reuse barrier
        for (int i = tid; i < HAL * HAL; i += 256) {
            int r = i / HAL, c = i - r * HAL;
            int y = ty0 + r - RAD, x = tx0 + c - RAD;
            float v = 0.0f;
            if ((unsigned)y < (unsigned)HW && (unsigned)x < (unsigned)HW)
                v = pbase[ch * PLANE + y * HW + x];
            phalo[r * HSTR + c] = v;
        }
        __syncthreads();
        for (int i = tid; i < HAL * TILE; i += 256) {
            int r = i >> 5, c = i & 31;
            const float* prow = &phalo[r * HSTR + c];
            const float* grow = &ghalo[r * HSTR + c];
            float s = 0.f, sg = 0.f;
            #pragma unroll
            for (int k = 0; k < 31; ++k) { float v = prow[k]; s += v; sg += v * grow[k]; }
            hsum0[r * TILE + c] = s;
            hsum1[r * TILE + c] = sg;
        }
        __syncthreads();
        #pragma unroll
        for (int q = 0; q < 4; ++q) {
            int o = q * 256 + tid;
            int r = o >> 5, c = o & 31;
            int y = ty0 + r, x = tx0 + c;
            float s = 0.f, sg = 0.f;
            #pragma unroll
            for (int k = 0; k < 31; ++k) {
                s  += hsum0[(r + k) * TILE + c];
                sg += hsum1[(r + k) * TILE + c];
            }
            float mp     = s  * INV_K2;
            float corrIp = sg * INV_K2;
            float cov    = corrIp - meanI[q] * mp;
            float aa     = cov / (varI[q] + 1e-6f);
            float bb     = mp - aa * meanI[q];
            size_t off = ((size_t)(b * 3 + ch) * HW + y) * HW + x;
            a_out[off] = aa;
            b_out[off] = bb;
        }
    }
}

__global__ __launch_bounds__(256) void gf_stage2(
    const float* __restrict__ guide,
    const float* __restrict__ a_in, const float* __restrict__ b_in,
    float* __restrict__ out)
{
    __shared__ float ahalo[HAL * HSTR];
    __shared__ float bhalo[HAL * HSTR];
    __shared__ float hsum0[HAL * TILE];
    __shared__ float hsum1[HAL * TILE];

    const int tx0 = blockIdx.x * TILE;
    const int ty0 = blockIdx.y * TILE;
    const int bc  = blockIdx.z;          // b*3 + ch
    const int b   = bc / 3;
    const int tid = threadIdx.x;

    const float* abase = a_in + (size_t)bc * PLANE;
    const float* bbase = b_in + (size_t)bc * PLANE;

    for (int i = tid; i < HAL * HAL; i += 256) {
        int r = i / HAL, c = i - r * HAL;
        int y = ty0 + r - RAD, x = tx0 + c - RAD;
        float va = 0.f, vb = 0.f;
        if ((unsigned)y < (unsigned)HW && (unsigned)x < (unsigned)HW) {
            int off = y * HW + x;
            va = abase[off]; vb = bbase[off];
        }
        ahalo[r * HSTR + c] = va;
        bhalo[r * HSTR + c] = vb;
    }
    __syncthreads();

    for (int i = tid; i < HAL * TILE; i += 256) {
        int r = i >> 5, c = i & 31;
        const float* ra = &ahalo[r * HSTR + c];
        const float* rb = &bhalo[r * HSTR + c];
        float sa = 0.f, sb = 0.f;
        #pragma unroll
        for (int k = 0; k < 31; ++k) { sa += ra[k]; sb += rb[k]; }
        hsum0[r * TILE + c] = sa;
        hsum1[r * TILE + c] = sb;
    }
    __syncthreads();

    const float* gbase = guide + (size_t)b * 3 * PLANE;
    #pragma unroll
    for (int q = 0; q < 4; ++q) {
        int o = q * 256 + tid;
        int r = o >> 5, c = o & 31;
        int y = ty0 + r, x = tx0 + c;
        float sa = 0.f, sb = 0.f;
        #pragma unroll
        for (int k = 0; k < 31; ++k) {
            sa += hsum0[(r + k) * TILE + c];
            sb += hsum1[(r + k) * TILE + c];
        }
        int off = y * HW + x;
        float gray = 0.299f * gbase[off] + 0.587f * gbase[PLANE + off]
                   + 0.114f * gbase[2 * PLANE + off];
        out[(size_t)bc * PLANE + off] = sa * INV_K2 * gray + sb * INV_K2;
    }
}

extern "C" void kernel_launch(void* const* d_in, const int* in_sizes, int n_in,
                              void* d_out, int out_size, void* d_ws, size_t ws_size,
                              hipStream_t stream)
{
    const float* guide = (const float*)d_in[0];
    const float* inp   = (const float*)d_in[1];
    float* out  = (float*)d_out;

    // workspace: a (6291456 f32) | b (6291456 f32)  => 48 MB
    float* a_ws = (float*)d_ws;
    float* b_ws = a_ws + (size_t)8 * 3 * PLANE;

    dim3 block(256);
    dim3 grid1(HW / TILE, HW / TILE, 8);
    gf_stage1<<<grid1, block, 0, stream>>>(guide, inp, a_ws, b_ws);

    dim3 grid2(HW / TILE, HW / TILE, 24);
    gf_stage2<<<grid2, block, 0, stream>>>(guide, a_ws, b_ws, out);
}

// Round 2
// 226.851 us; speedup vs baseline: 1.3875x; 1.3875x over previous
//
#include <hip/hip_runtime.h>
#include <hip/hip_bf16.h>

// Guided filter, B=8 C=3 H=W=512, RADIUS=15 (31x31 box, zero-pad, /961 always).
// R2: sliding-window separable box sums (quartered for fp32 accuracy),
//     float2-packed plane pairs so each ds_read_b64 feeds two accumulators.
// Stage 1: per 32x32 tile -> a,b planes (interleaved float2) in workspace.
// Stage 2: box(a), box(b) + recompute gray at center -> output.

#define TILE 32
#define RAD 15
#define HAL 62          // TILE + 2*RAD
#define GSTR 63         // halo row stride in float2 (+1 pad)
#define SSTR 33         // hsum row stride in float2 (+1 pad; avoids 62-way write conflict)
#define HW 512
#define PLANE 262144    // 512*512
#define INV_K2 (1.0f / 961.0f)

__global__ __launch_bounds__(256) void gf_stage1(
    const float* __restrict__ guide, const float* __restrict__ inp,
    float2* __restrict__ ab)
{
    __shared__ float2 gp[HAL * GSTR];   // .x = gray, .y = current input channel
    __shared__ float2 hs[HAL * SSTR];   // horizontal sums {s0, s1}

    const int tx0 = blockIdx.x * TILE;
    const int ty0 = blockIdx.y * TILE;
    const int b   = blockIdx.z;
    const int tid = threadIdx.x;

    const float* gbase = guide + (size_t)b * 3 * PLANE;
    const float* pbase = inp   + (size_t)b * 3 * PLANE;

    // ---- gray halo (luma on the fly), zero outside image ----
    for (int i = tid; i < HAL * HAL; i += 256) {
        int r = i / HAL, c = i - r * HAL;
        int y = ty0 + r - RAD, x = tx0 + c - RAD;
        float v = 0.0f;
        if ((unsigned)y < (unsigned)HW && (unsigned)x < (unsigned)HW) {
            int off = y * HW + x;
            v = 0.299f * gbase[off] + 0.587f * gbase[PLANE + off]
              + 0.114f * gbase[2 * PLANE + off];
        }
        gp[r * GSTR + c] = make_float2(v, 0.0f);
    }
    __syncthreads();

    // ---- H pass A (gray, gray^2): wave q=tid>>6 owns cols q*8..q*8+7, lane = row ----
    {
        int r = tid & 63, q = tid >> 6;
        if (r < HAL) {
            const float2* row = &gp[r * GSTR + q * 8];
            float s0 = 0.f, s1 = 0.f;
            #pragma unroll
            for (int k = 0; k < 31; ++k) { float v = row[k].x; s0 += v; s1 += v * v; }
            float2* hrow = &hs[r * SSTR + q * 8];
            hrow[0] = make_float2(s0, s1);
            #pragma unroll
            for (int j = 1; j < 8; ++j) {
                float vi = row[j + 30].x, vo = row[j - 1].x;
                s0 += vi - vo;
                s1 += vi * vi - vo * vo;
                hrow[j] = make_float2(s0, s1);
            }
        }
    }
    __syncthreads();

    // ---- V pass A -> mean_I, var_I in registers (4 rows/thread) ----
    float meanI[4], varI[4];
    {
        int c = tid & 31, q = tid >> 5;       // q 0..7, rows q*4..q*4+3
        const float2* col = &hs[(q * 4) * SSTR + c];
        float s0 = 0.f, s1 = 0.f;
        #pragma unroll
        for (int k = 0; k < 31; ++k) { float2 v = col[k * SSTR]; s0 += v.x; s1 += v.y; }
        meanI[0] = s0 * INV_K2;
        varI[0]  = s1 * INV_K2 - meanI[0] * meanI[0];
        #pragma unroll
        for (int j = 1; j < 4; ++j) {
            float2 vi = col[(j + 30) * SSTR], vo = col[(j - 1) * SSTR];
            s0 += vi.x - vo.x;
            s1 += vi.y - vo.y;
            meanI[j] = s0 * INV_K2;
            varI[j]  = s1 * INV_K2 - meanI[j] * meanI[j];
        }
    }

    // ---- per input channel: mean_p, corr_Ip -> a,b (interleaved float2) ----
    for (int ch = 0; ch < 3; ++ch) {
        __syncthreads();   // prior readers of gp/hs done
        for (int i = tid; i < HAL * HAL; i += 256) {
            int r = i / HAL, c = i - r * HAL;
            int y = ty0 + r - RAD, x = tx0 + c - RAD;
            float v = 0.0f;
            if ((unsigned)y < (unsigned)HW && (unsigned)x < (unsigned)HW)
                v = pbase[ch * PLANE + y * HW + x];
            gp[r * GSTR + c].y = v;
        }
        __syncthreads();
        {
            int r = tid & 63, q = tid >> 6;
            if (r < HAL) {
                const float2* row = &gp[r * GSTR + q * 8];
                float s0 = 0.f, s1 = 0.f;
                #pragma unroll
                for (int k = 0; k < 31; ++k) { float2 v = row[k]; s0 += v.y; s1 += v.x * v.y; }
                float2* hrow = &hs[r * SSTR + q * 8];
                hrow[0] = make_float2(s0, s1);
                #pragma unroll
                for (int j = 1; j < 8; ++j) {
                    float2 vi = row[j + 30], vo = row[j - 1];
                    s0 += vi.y - vo.y;
                    s1 += vi.x * vi.y - vo.x * vo.y;
                    hrow[j] = make_float2(s0, s1);
                }
            }
        }
        __syncthreads();
        {
            int c = tid & 31, q = tid >> 5;
            const float2* col = &hs[(q * 4) * SSTR + c];
            float s0 = 0.f, s1 = 0.f;
            #pragma unroll
            for (int k = 0; k < 31; ++k) { float2 v = col[k * SSTR]; s0 += v.x; s1 += v.y; }
            float2* abp = ab + (size_t)(b * 3 + ch) * PLANE;
            #pragma unroll
            for (int j = 0; j < 4; ++j) {
                if (j) {
                    float2 vi = col[(j + 30) * SSTR], vo = col[(j - 1) * SSTR];
                    s0 += vi.x - vo.x;
                    s1 += vi.y - vo.y;
                }
                float mp   = s0 * INV_K2;
                float corr = s1 * INV_K2;
                float cov  = corr - meanI[j] * mp;
                float aa   = cov / (varI[j] + 1e-6f);
                float bb   = mp - aa * meanI[j];
                abp[(ty0 + q * 4 + j) * HW + tx0 + c] = make_float2(aa, bb);
            }
        }
    }
}

__global__ __launch_bounds__(256) void gf_stage2(
    const float* __restrict__ guide, const float2* __restrict__ ab,
    float* __restrict__ out)
{
    __shared__ float2 abh[HAL * GSTR];  // {a, b} halo
    __shared__ float2 hs[HAL * SSTR];   // {sa, sb}

    const int tx0 = blockIdx.x * TILE;
    const int ty0 = blockIdx.y * TILE;
    const int bc  = blockIdx.z;          // b*3 + ch
    const int b   = bc / 3;
    const int tid = threadIdx.x;

    const float2* abp = ab + (size_t)bc * PLANE;

    for (int i = tid; i < HAL * HAL; i += 256) {
        int r = i / HAL, c = i - r * HAL;
        int y = ty0 + r - RAD, x = tx0 + c - RAD;
        float2 v = make_float2(0.f, 0.f);
        if ((unsigned)y < (unsigned)HW && (unsigned)x < (unsigned)HW)
            v = abp[y * HW + x];
        abh[r * GSTR + c] = v;
    }
    __syncthreads();

    {
        int r = tid & 63, q = tid >> 6;
        if (r < HAL) {
            const float2* row = &abh[r * GSTR + q * 8];
            float s0 = 0.f, s1 = 0.f;
            #pragma unroll
            for (int k = 0; k < 31; ++k) { float2 v = row[k]; s0 += v.x; s1 += v.y; }
            float2* hrow = &hs[r * SSTR + q * 8];
            hrow[0] = make_float2(s0, s1);
            #pragma unroll
            for (int j = 1; j < 8; ++j) {
                float2 vi = row[j + 30], vo = row[j - 1];
                s0 += vi.x - vo.x;
                s1 += vi.y - vo.y;
                hrow[j] = make_float2(s0, s1);
            }
        }
    }
    __syncthreads();

    {
        int c = tid & 31, q = tid >> 5;
        const float2* col = &hs[(q * 4) * SSTR + c];
        float s0 = 0.f, s1 = 0.f;
        #pragma unroll
        for (int k = 0; k < 31; ++k) { float2 v = col[k * SSTR]; s0 += v.x; s1 += v.y; }
        const float* gbase = guide + (size_t)b * 3 * PLANE;
        #pragma unroll
        for (int j = 0; j < 4; ++j) {
            if (j) {
                float2 vi = col[(j + 30) * SSTR], vo = col[(j - 1) * SSTR];
                s0 += vi.x - vo.x;
                s1 += vi.y - vo.y;
            }
            int off = (ty0 + q * 4 + j) * HW + tx0 + c;
            float gray = 0.299f * gbase[off] + 0.587f * gbase[PLANE + off]
                       + 0.114f * gbase[2 * PLANE + off];
            out[(size_t)bc * PLANE + off] = s0 * INV_K2 * gray + s1 * INV_K2;
        }
    }
}

extern "C" void kernel_launch(void* const* d_in, const int* in_sizes, int n_in,
                              void* d_out, int out_size, void* d_ws, size_t ws_size,
                              hipStream_t stream)
{
    const float* guide = (const float*)d_in[0];
    const float* inp   = (const float*)d_in[1];
    float* out  = (float*)d_out;

    // workspace: interleaved {a,b} float2, 24 planes => 50.3 MB (same bytes as before)
    float2* ab_ws = (float2*)d_ws;

    dim3 block(256);
    dim3 grid1(HW / TILE, HW / TILE, 8);
    gf_stage1<<<grid1, block, 0, stream>>>(guide, inp, ab_ws);

    dim3 grid2(HW / TILE, HW / TILE, 24);
    gf_stage2<<<grid2, block, 0, stream>>>(guide, ab_ws, out);
}

// Round 3
// 176.583 us; speedup vs baseline: 1.7824x; 1.2847x over previous
//
#include <hip/hip_runtime.h>
#include <hip/hip_bf16.h>

// Guided filter, B=8 C=3 H=W=512, RADIUS=15 (31x31 box, zero-pad, /961).
// R3: sliding windows kept; LDS switched to SoA float with ODD dword strides
//     (float2 had even dword stride -> 4-way bank conflict on every b64).
//     Register-prefetched halos hide global latency; fewer barriers.

#define TILE 32
#define RAD 15
#define HAL 62          // TILE + 2*RAD
#define GS 63           // halo row stride (floats, odd -> conflict-free)
#define SS 33           // hsum row stride (floats, odd -> conflict-free)
#define HW 512
#define PLANE 262144    // 512*512
#define INV_K2 (1.0f / 961.0f)

__global__ __launch_bounds__(256) void gf_stage1(
    const float* __restrict__ guide, const float* __restrict__ inp,
    float2* __restrict__ ab)
{
    __shared__ float gh[HAL * GS];   // gray halo
    __shared__ float ph[HAL * GS];   // current-channel input halo
    __shared__ float h0[HAL * SS];   // horizontal sums
    __shared__ float h1[HAL * SS];

    const int tx0 = blockIdx.x * TILE;
    const int ty0 = blockIdx.y * TILE;
    const int b   = blockIdx.z;
    const int tid = threadIdx.x;

    const float* gbase = guide + (size_t)b * 3 * PLANE;
    const float* pbase = inp   + (size_t)b * 3 * PLANE;

    // ---- per-thread halo slots: LDS index + global offset (-1 = zero/skip) ----
    int lidx[16], goff[16];
    #pragma unroll
    for (int k = 0; k < 16; ++k) {
        int i = tid + k * 256;
        int r = i / HAL, c = i - r * HAL;
        bool inh = i < HAL * HAL;
        lidx[k] = inh ? (r * GS + c) : -1;
        int y = ty0 + r - RAD, x = tx0 + c - RAD;
        bool ok = inh && ((unsigned)y < (unsigned)HW) && ((unsigned)x < (unsigned)HW);
        goff[k] = ok ? (y * HW + x) : -1;
    }

    // ---- prefetch gray (3 planes) + p channel 0 ----
    float gr_[16], pA[16];
    #pragma unroll
    for (int k = 0; k < 16; ++k) {
        float g = 0.f, p = 0.f;
        if (goff[k] >= 0) {
            int o = goff[k];
            g = 0.299f * gbase[o] + 0.587f * gbase[PLANE + o]
              + 0.114f * gbase[2 * PLANE + o];
            p = pbase[o];
        }
        gr_[k] = g; pA[k] = p;
    }
    #pragma unroll
    for (int k = 0; k < 16; ++k)
        if (lidx[k] >= 0) { gh[lidx[k]] = gr_[k]; ph[lidx[k]] = pA[k]; }
    __syncthreads();                                            // bar0

    // H-pass mapping: lane = row, wave = 8-col group
    const int hr = tid & 63, hq = tid >> 6;
    const bool hact = hr < HAL;
    const int hbase = hr * GS + hq * 8;
    const int obase = hr * SS + hq * 8;
    // V-pass mapping: lane = col, q = 4-row group
    const int vc = tid & 31, vq = tid >> 5;
    const int vbase = (vq * 4) * SS + vc;

    // ---- H gray: sum g, sum g^2 ----
    if (hact) {
        float s0 = 0.f, s1 = 0.f;
        #pragma unroll
        for (int k = 0; k < 31; ++k) { float v = gh[hbase + k]; s0 += v; s1 += v * v; }
        h0[obase] = s0; h1[obase] = s1;
        #pragma unroll
        for (int j = 1; j < 8; ++j) {
            float vi = gh[hbase + j + 30], vo = gh[hbase + j - 1];
            s0 += vi - vo; s1 += vi * vi - vo * vo;
            h0[obase + j] = s0; h1[obase + j] = s1;
        }
    }
    __syncthreads();                                            // bar1

    // ---- V gray -> mean_I, var_I (registers) ----
    float meanI[4], varI[4];
    {
        float s0 = 0.f, s1 = 0.f;
        #pragma unroll
        for (int k = 0; k < 31; ++k) { s0 += h0[vbase + k * SS]; s1 += h1[vbase + k * SS]; }
        meanI[0] = s0 * INV_K2; varI[0] = s1 * INV_K2 - meanI[0] * meanI[0];
        #pragma unroll
        for (int j = 1; j < 4; ++j) {
            s0 += h0[vbase + (j + 30) * SS] - h0[vbase + (j - 1) * SS];
            s1 += h1[vbase + (j + 30) * SS] - h1[vbase + (j - 1) * SS];
            meanI[j] = s0 * INV_K2; varI[j] = s1 * INV_K2 - meanI[j] * meanI[j];
        }
    }

    // prefetch p channel 1 (lands during H/V of ch0)
    float pB[16];
    #pragma unroll
    for (int k = 0; k < 16; ++k)
        pB[k] = (goff[k] >= 0) ? pbase[PLANE + goff[k]] : 0.f;

    // ---- channel phases ----
    // CH_H: H-pass (sum p, sum g*p); CH_V: V-pass -> a,b write
#define CH_H                                                                 \
    if (hact) {                                                              \
        float s0 = 0.f, s1 = 0.f;                                            \
        _Pragma("unroll")                                                    \
        for (int k = 0; k < 31; ++k) {                                       \
            float p = ph[hbase + k], g = gh[hbase + k];                      \
            s0 += p; s1 += g * p;                                            \
        }                                                                    \
        h0[obase] = s0; h1[obase] = s1;                                      \
        _Pragma("unroll")                                                    \
        for (int j = 1; j < 8; ++j) {                                        \
            float pi = ph[hbase + j + 30], po = ph[hbase + j - 1];           \
            float gi = gh[hbase + j + 30], go = gh[hbase + j - 1];           \
            s0 += pi - po; s1 += gi * pi - go * po;                          \
            h0[obase + j] = s0; h1[obase + j] = s1;                          \
        }                                                                    \
    }

#define CH_V(ch)                                                             \
    {                                                                        \
        float s0 = 0.f, s1 = 0.f;                                            \
        _Pragma("unroll")                                                    \
        for (int k = 0; k < 31; ++k) { s0 += h0[vbase + k * SS]; s1 += h1[vbase + k * SS]; } \
        float2* abp = ab + (size_t)(b * 3 + (ch)) * PLANE;                   \
        _Pragma("unroll")                                                    \
        for (int j = 0; j < 4; ++j) {                                        \
            if (j) {                                                         \
                s0 += h0[vbase + (j + 30) * SS] - h0[vbase + (j - 1) * SS];  \
                s1 += h1[vbase + (j + 30) * SS] - h1[vbase + (j - 1) * SS];  \
            }                                                                \
            float mp = s0 * INV_K2, corr = s1 * INV_K2;                      \
            float cov = corr - meanI[j] * mp;                                \
            float aa  = cov / (varI[j] + 1e-6f);                             \
            float bb  = mp - aa * meanI[j];                                  \
            abp[(ty0 + vq * 4 + j) * HW + tx0 + vc] = make_float2(aa, bb);   \
        }                                                                    \
    }

    __syncthreads();                                            // bar2: h free
    CH_H                                                        // ch0
    __syncthreads();                                            // bar3: h ready, ph free
    CH_V(0)
    #pragma unroll
    for (int k = 0; k < 16; ++k) if (lidx[k] >= 0) ph[lidx[k]] = pB[k];
    // prefetch p channel 2
    float pC[16];
    #pragma unroll
    for (int k = 0; k < 16; ++k)
        pC[k] = (goff[k] >= 0) ? pbase[2 * PLANE + goff[k]] : 0.f;

    __syncthreads();                                            // bar4
    CH_H                                                        // ch1
    __syncthreads();                                            // bar5
    CH_V(1)
    #pragma unroll
    for (int k = 0; k < 16; ++k) if (lidx[k] >= 0) ph[lidx[k]] = pC[k];

    __syncthreads();                                            // bar6
    CH_H                                                        // ch2
    __syncthreads();                                            // bar7
    CH_V(2)
#undef CH_H
#undef CH_V
}

__global__ __launch_bounds__(256) void gf_stage2(
    const float* __restrict__ guide, const float2* __restrict__ ab,
    float* __restrict__ out)
{
    __shared__ float ah[HAL * GS];
    __shared__ float bh[HAL * GS];
    __shared__ float h0[HAL * SS];
    __shared__ float h1[HAL * SS];

    const int tx0 = blockIdx.x * TILE;
    const int ty0 = blockIdx.y * TILE;
    const int bc  = blockIdx.z;          // b*3 + ch
    const int b   = bc / 3;
    const int tid = threadIdx.x;

    const float2* abp = ab + (size_t)bc * PLANE;
    const float*  gb  = guide + (size_t)b * 3 * PLANE;

    const int vc = tid & 31, vq = tid >> 5;

    // prefetch a,b halo + center gray
    int lidx[16];
    float2 hv[16];
    #pragma unroll
    for (int k = 0; k < 16; ++k) {
        int i = tid + k * 256;
        int r = i / HAL, c = i - r * HAL;
        bool inh = i < HAL * HAL;
        lidx[k] = inh ? (r * GS + c) : -1;
        int y = ty0 + r - RAD, x = tx0 + c - RAD;
        bool ok = inh && ((unsigned)y < (unsigned)HW) && ((unsigned)x < (unsigned)HW);
        hv[k] = ok ? abp[y * HW + x] : make_float2(0.f, 0.f);
    }
    float gcen[4];
    #pragma unroll
    for (int j = 0; j < 4; ++j) {
        int o = (ty0 + vq * 4 + j) * HW + tx0 + vc;
        gcen[j] = 0.299f * gb[o] + 0.587f * gb[PLANE + o] + 0.114f * gb[2 * PLANE + o];
    }

    #pragma unroll
    for (int k = 0; k < 16; ++k)
        if (lidx[k] >= 0) { ah[lidx[k]] = hv[k].x; bh[lidx[k]] = hv[k].y; }
    __syncthreads();

    const int hr = tid & 63, hq = tid >> 6;
    const int hbase = hr * GS + hq * 8;
    const int obase = hr * SS + hq * 8;
    if (hr < HAL) {
        float s0 = 0.f, s1 = 0.f;
        #pragma unroll
        for (int k = 0; k < 31; ++k) { s0 += ah[hbase + k]; s1 += bh[hbase + k]; }
        h0[obase] = s0; h1[obase] = s1;
        #pragma unroll
        for (int j = 1; j < 8; ++j) {
            s0 += ah[hbase + j + 30] - ah[hbase + j - 1];
            s1 += bh[hbase + j + 30] - bh[hbase + j - 1];
            h0[obase + j] = s0; h1[obase + j] = s1;
        }
    }
    __syncthreads();

    {
        const int vbase = (vq * 4) * SS + vc;
        float s0 = 0.f, s1 = 0.f;
        #pragma unroll
        for (int k = 0; k < 31; ++k) { s0 += h0[vbase + k * SS]; s1 += h1[vbase + k * SS]; }
        float* op = out + (size_t)bc * PLANE;
        #pragma unroll
        for (int j = 0; j < 4; ++j) {
            if (j) {
                s0 += h0[vbase + (j + 30) * SS] - h0[vbase + (j - 1) * SS];
                s1 += h1[vbase + (j + 30) * SS] - h1[vbase + (j - 1) * SS];
            }
            int o = (ty0 + vq * 4 + j) * HW + tx0 + vc;
            op[o] = s0 * INV_K2 * gcen[j] + s1 * INV_K2;
        }
    }
}

extern "C" void kernel_launch(void* const* d_in, const int* in_sizes, int n_in,
                              void* d_out, int out_size, void* d_ws, size_t ws_size,
                              hipStream_t stream)
{
    const float* guide = (const float*)d_in[0];
    const float* inp   = (const float*)d_in[1];
    float* out  = (float*)d_out;

    float2* ab_ws = (float2*)d_ws;   // 24 planes of interleaved {a,b} = 50.3 MB

    dim3 block(256);
    dim3 grid1(HW / TILE, HW / TILE, 8);
    gf_stage1<<<grid1, block, 0, stream>>>(guide, inp, ab_ws);

    dim3 grid2(HW / TILE, HW / TILE, 24);
    gf_stage2<<<grid2, block, 0, stream>>>(guide, ab_ws, out);
}